// Round 7
// baseline (358.332 us; speedup 1.0000x reference)
//
#include <hip/hip_runtime.h>
#include <cstdint>
#include <cmath>

// ---------------------------------------------------------------------------
// MHKPattLayer fused kernel for MI355X (gfx950) — round 7 (r6 + compile fix)
// Cross-tile software pipeline in one persistent block per CU:
//   step i: QK+stats+GELU+pack(tile i)  INTERLEAVED with  PV(tile i-1).
// 16 waves, grid 256 (1 block/CU, 4 tiles of 64 q-rows each).
// QK: 3-pass split (K hi/lo bf16 from ws; Q hi bf16 + Q lo fp8-e4m3 in LDS).
// PV: per wave (v-16col, n-half), 16-reg acc, partials combined by exactly-2
//     deterministic atomicAdds into pre-zeroed out.
// LDS: S 128K + Qhi 16K + Qlo 8K + red 4K = 159744 B.
// B=4, T=2048, C=1024, H=8, N=1024, Dk=Dv=128
// ---------------------------------------------------------------------------

typedef __bf16 bf16x8 __attribute__((ext_vector_type(8)));
typedef float  f32x16 __attribute__((ext_vector_type(16)));
typedef float  f32x4  __attribute__((ext_vector_type(4)));
typedef unsigned short u16x8 __attribute__((ext_vector_type(8)));

#if defined(__has_builtin)
#if __has_builtin(__builtin_amdgcn_cvt_pk_f32_fp8) && __has_builtin(__builtin_amdgcn_cvt_pk_fp8_f32)
#define HW_FP8 1
#endif
#endif
#ifndef HW_FP8
#define HW_FP8 0
#endif

__device__ __forceinline__ unsigned short bfbits(__bf16 b) {
  return __builtin_bit_cast(unsigned short, b);
}

// ---- fp8 e4m3 storage of q_lo*1024 (all-normal range; tiny values -> 0) ----
__device__ __forceinline__ unsigned int enc_fp8_1(float f) {
  // RNE f32 -> e4m3 for |f| <= ~9 (no overflow possible here)
  unsigned int u = __float_as_uint(f);
  unsigned int s = u >> 31;
  u &= 0x7FFFFFFFu;
  unsigned int r = (u + 0x7FFFFu + ((u >> 20) & 1u)) >> 20;
  unsigned int mag = (r >= 968u) ? (r - 960u) : 0u;  // e>=1 only; else flush
  if (mag > 127u) mag = 127u;
  return (s << 7) | mag;
}

template <bool WORD>
__device__ __forceinline__ unsigned int pack_fp8_pair(float a, float b,
                                                      unsigned int old) {
#if HW_FP8
  return (unsigned int)__builtin_amdgcn_cvt_pk_fp8_f32(a, b, (int)old, WORD);
#else
  const unsigned int pk = enc_fp8_1(a) | (enc_fp8_1(b) << 8);
  return WORD ? ((old & 0x0000FFFFu) | (pk << 16))
              : ((old & 0xFFFF0000u) | pk);
#endif
}

__device__ __forceinline__ unsigned short dec_fp8_1(unsigned int b) {
  // e4m3 (value*1024) -> bf16(value):  exp' = e - 7 - 10 + 127 = e + 110
  const unsigned int t = b & 0x7Fu;
  unsigned int v = (t << 4) + 14080u;   // (e+110)<<7 | m<<4
  v |= (b & 0x80u) << 8;
  return (t >= 16u) ? (unsigned short)v : (unsigned short)0;
}

__device__ __forceinline__ bf16x8 dec_qlo(uint2 lo) {
#if HW_FP8
  const float S = 1.0f / 1024.0f;
  auto p0 = __builtin_amdgcn_cvt_pk_f32_fp8((int)lo.x, false);
  auto p1 = __builtin_amdgcn_cvt_pk_f32_fp8((int)lo.x, true);
  auto p2 = __builtin_amdgcn_cvt_pk_f32_fp8((int)lo.y, false);
  auto p3 = __builtin_amdgcn_cvt_pk_f32_fp8((int)lo.y, true);
  unsigned int w0, w1, w2, w3;
  asm("v_cvt_pk_bf16_f32 %0, %1, %2" : "=v"(w0) : "v"(p0[0] * S), "v"(p0[1] * S));
  asm("v_cvt_pk_bf16_f32 %0, %1, %2" : "=v"(w1) : "v"(p1[0] * S), "v"(p1[1] * S));
  asm("v_cvt_pk_bf16_f32 %0, %1, %2" : "=v"(w2) : "v"(p2[0] * S), "v"(p2[1] * S));
  asm("v_cvt_pk_bf16_f32 %0, %1, %2" : "=v"(w3) : "v"(p3[0] * S), "v"(p3[1] * S));
  uint4 uu = make_uint4(w0, w1, w2, w3);
  return __builtin_bit_cast(bf16x8, uu);
#else
  unsigned short r0 = dec_fp8_1(lo.x & 0xFFu);
  unsigned short r1 = dec_fp8_1((lo.x >> 8) & 0xFFu);
  unsigned short r2 = dec_fp8_1((lo.x >> 16) & 0xFFu);
  unsigned short r3 = dec_fp8_1(lo.x >> 24);
  unsigned short r4 = dec_fp8_1(lo.y & 0xFFu);
  unsigned short r5 = dec_fp8_1((lo.y >> 8) & 0xFFu);
  unsigned short r6 = dec_fp8_1((lo.y >> 16) & 0xFFu);
  unsigned short r7 = dec_fp8_1(lo.y >> 24);
  uint4 uu = make_uint4((unsigned)r0 | ((unsigned)r1 << 16),
                        (unsigned)r2 | ((unsigned)r3 << 16),
                        (unsigned)r4 | ((unsigned)r5 << 16),
                        (unsigned)r6 | ((unsigned)r7 << 16));
  return __builtin_bit_cast(bf16x8, uu);
#endif
}

// exact GELU, scale pre-folded (A&S 7.1.28, |eps|<=3e-7)
__device__ __forceinline__ float gelu_s(float raw, float c707, float chalf) {
  const float s = raw * c707;
  const float a = fabsf(s);
  float u = fmaf(a, 4.30638e-5f, 2.765672e-4f);
  u = fmaf(u, a, 1.520143e-4f);
  u = fmaf(u, a, 9.2705272e-3f);
  u = fmaf(u, a, 4.22820123e-2f);
  u = fmaf(u, a, 7.05230784e-2f);
  u = fmaf(u, a, 1.0f);
  const float r  = __builtin_amdgcn_rcpf(u);
  const float r2 = r * r;
  const float r4 = r2 * r2;
  const float r8 = r4 * r4;
  const float er = copysignf(1.0f - r8 * r8, s);
  const float hf = raw * chalf;
  return fmaf(hf, er, hf);
}

// ---------------- prep kernel ----------------
__global__ void prep_kv(const float* __restrict__ key,
                        const float* __restrict__ val,
                        unsigned short* __restrict__ kh,
                        unsigned short* __restrict__ kl,
                        unsigned short* __restrict__ vp) {
  const int gid = blockIdx.x * 256 + threadIdx.x;   // 0..262143
  if (gid < 131072) {
    const int h  = gid >> 14;
    const int kc = (gid >> 10) & 15;
    const int n  = gid & 1023;
    const float* src = key + ((size_t)(h << 10) + n) * 128 + kc * 8;
    const float4 f0 = *(const float4*)src;
    const float4 f1 = *(const float4*)(src + 4);
    const float fv[8] = {f0.x, f0.y, f0.z, f0.w, f1.x, f1.y, f1.z, f1.w};
    u16x8 hv, lv;
#pragma unroll
    for (int e = 0; e < 8; ++e) {
      const __bf16 hb = (__bf16)fv[e];
      hv[e] = bfbits(hb);
      lv[e] = bfbits((__bf16)(fv[e] - (float)hb));
    }
    const size_t o = ((size_t)(h * 16 + kc) * 1024 + n) * 8;
    *(u16x8*)(kh + o) = hv;
    *(u16x8*)(kl + o) = lv;
  } else {
    const int tid = gid - 131072;
    const int h   = tid >> 14;
    const int s2  = (tid >> 7) & 127;
    const int v   = tid & 127;
    const float* src = val + ((size_t)(h << 10) + s2 * 8) * 128 + v;
    u16x8 ov;
#pragma unroll
    for (int e = 0; e < 8; ++e) ov[e] = bfbits((__bf16)src[(size_t)e * 128]);
    *(u16x8*)(vp + ((size_t)(h * 128 + s2) * 128 + v) * 8) = ov;
  }
}

// ---------------- fused pipelined kernel ----------------
// LDS: [0,131072) S granules (ng=n/8<128, q<64): byte=(ng*64+(q^(ng&7)))*16
//      [131072,147456) Q-hi bf16 granules g=kc*64+(r^((kc>>1)&7)), 16B each
//      [147456,155648) Q-lo fp8 granules, 8B each
//      [155648,159744) red [16][64] f32 (ss then gs, separated by barriers)
#define QHI_OFF 131072
#define QLO_OFF 147456
#define RED_OFF 155648
#define SMEMSZ  159744

__global__ __launch_bounds__(1024, 4) void fused_mhk(
    const float* __restrict__ x,
    const unsigned short* __restrict__ k_hi,
    const unsigned short* __restrict__ k_lo,
    const unsigned short* __restrict__ v_pk,
    float* __restrict__ out)
{
  extern __shared__ char smem[];
  const int tid  = threadIdx.x;
  const int wave = tid >> 6;
  const int lane = tid & 63;
  const int l31  = lane & 31;
  const int hi   = lane >> 5;
  const int l15  = lane & 15;
  const int l4   = lane >> 4;

  const int bid = blockIdx.x;          // 256 blocks
  const int h   = bid & 7;             // head per XCD slot
  const int chunk = bid >> 3;          // 0..31
  const int b   = chunk >> 3;
  const int t0base = (chunk & 7) * 256;

  const unsigned short* kph = k_hi + (size_t)h * 131072;
  const unsigned short* kpl = k_lo + (size_t)h * 131072;
  const unsigned short* vph = v_pk + (size_t)h * 131072;
  float* red = (float*)(smem + RED_OFF);

  const int pc = wave & 7;    // PV: 16-wide v column
  const int pn = wave >> 3;   // PV: n-half

  // ---- stage Q(tile 0)
  {
    const float* xq = x + ((size_t)(b * 2048 + t0base)) * 1024 + h * 128;
    const int r = tid >> 4, kc = tid & 15;
    const float* sp = xq + (size_t)r * 1024 + kc * 8;
    const float4 f0 = *(const float4*)sp;
    const float4 f1 = *(const float4*)(sp + 4);
    const float fv[8] = {f0.x, f0.y, f0.z, f0.w, f1.x, f1.y, f1.z, f1.w};
    bf16x8 hv; float lv[8];
#pragma unroll
    for (int e = 0; e < 8; ++e) {
      const __bf16 hb = (__bf16)fv[e];
      hv[e] = hb;
      lv[e] = (fv[e] - (float)hb) * 1024.0f;
    }
    const int g = kc * 64 + (r ^ ((kc >> 1) & 7));
    *(bf16x8*)(smem + QHI_OFF + g * 16) = hv;
    unsigned int w0 = pack_fp8_pair<false>(lv[0], lv[1], 0u);
    w0 = pack_fp8_pair<true>(lv[2], lv[3], w0);
    unsigned int w1 = pack_fp8_pair<false>(lv[4], lv[5], 0u);
    w1 = pack_fp8_pair<true>(lv[6], lv[7], w1);
    *(uint2*)(smem + QLO_OFF + g * 8) = make_uint2(w0, w1);
  }
  __syncthreads();

  f32x16 acc[2][2];
  f32x4 pv[4];
  float gs0 = 0.f, gs1 = 0.f;

  for (int i = 0; i <= 4; ++i) {
    const bool hasP = (i < 4);
    const bool hasC = (i >= 1);

    if (hasP) {
#pragma unroll
      for (int t = 0; t < 2; ++t)
#pragma unroll
        for (int qt = 0; qt < 2; ++qt)
#pragma unroll
          for (int e = 0; e < 16; ++e) acc[t][qt][e] = 0.f;
    }
    if (hasC) {
#pragma unroll
      for (int qs = 0; qs < 4; ++qs)
#pragma unroll
        for (int j = 0; j < 4; ++j) pv[qs][j] = 0.f;
    }

    // ============ segA: QK(i) interleaved with PV(i-1) ks 0..7 ============
    const size_t kb = (size_t)hi * 8192 + (size_t)(wave * 64 + l31) * 8;
#pragma unroll
    for (int u = 0; u < 8; ++u) {
      if (hasP) {
        const int s = u;
        bf16x8 bqh[2], bql[2];
#pragma unroll
        for (int qt = 0; qt < 2; ++qt) {
          const int gx = (2 * s + hi) * 64 + ((qt * 32 + l31) ^ s);
          bqh[qt] = *(const bf16x8*)(smem + QHI_OFF + gx * 16);
          bql[qt] = dec_qlo(*(const uint2*)(smem + QLO_OFF + gx * 8));
        }
        const unsigned short* kah = kph + kb + s * 16384;
        const unsigned short* kal = kpl + kb + s * 16384;
#pragma unroll
        for (int t = 0; t < 2; ++t) {
          const bf16x8 ah = *(const bf16x8*)(kah + t * 256);
          const bf16x8 al = *(const bf16x8*)(kal + t * 256);
          acc[t][0] = __builtin_amdgcn_mfma_f32_32x32x16_bf16(ah, bqh[0], acc[t][0], 0, 0, 0);
          acc[t][1] = __builtin_amdgcn_mfma_f32_32x32x16_bf16(ah, bqh[1], acc[t][1], 0, 0, 0);
          acc[t][0] = __builtin_amdgcn_mfma_f32_32x32x16_bf16(ah, bql[0], acc[t][0], 0, 0, 0);
          acc[t][1] = __builtin_amdgcn_mfma_f32_32x32x16_bf16(ah, bql[1], acc[t][1], 0, 0, 0);
          acc[t][0] = __builtin_amdgcn_mfma_f32_32x32x16_bf16(al, bqh[0], acc[t][0], 0, 0, 0);
          acc[t][1] = __builtin_amdgcn_mfma_f32_32x32x16_bf16(al, bqh[1], acc[t][1], 0, 0, 0);
        }
      }
      if (hasC) {
        const int s2 = pn * 64 + u * 4 + l4;
        const bf16x8 bb = *(const bf16x8*)(vph + ((size_t)s2 * 128 + pc * 16 + l15) * 8);
        const char* arow = smem + (size_t)s2 * 1024;
#pragma unroll
        for (int qs = 0; qs < 4; ++qs) {
          const int q = qs * 16 + l15;
          const bf16x8 aa = *(const bf16x8*)(arow + (q ^ (s2 & 7)) * 16);
          pv[qs] = __builtin_amdgcn_mfma_f32_16x16x32_bf16(aa, bb, pv[qs], 0, 0, 0);
        }
      }
    }
    if (hasP) {  // ss partials -> red
      float ss0 = 0.f, ss1 = 0.f;
#pragma unroll
      for (int t = 0; t < 2; ++t)
#pragma unroll
        for (int e = 0; e < 16; ++e) {
          ss0 += acc[t][0][e] * acc[t][0][e];
          ss1 += acc[t][1][e] * acc[t][1][e];
        }
      ss0 += __shfl_xor(ss0, 32);
      ss1 += __shfl_xor(ss1, 32);
      red[wave * 64 + lane] = hi ? ss1 : ss0;
    }
    __syncthreads();

    // ===== segB1: scale+GELU(i) ∥ PV(i-1) ks 8..15 ∥ stage Q(i+1) =====
    if (hasP) {
      float sum0 = 0.f, sum1 = 0.f;
#pragma unroll
      for (int w = 0; w < 16; ++w) {
        sum0 += red[w * 64 + l31];
        sum1 += red[w * 64 + 32 + l31];
      }
      const float scale0 = 32.0f / fmaxf(sqrtf(sum0), 1e-8f);
      const float scale1 = 32.0f / fmaxf(sqrtf(sum1), 1e-8f);
      const float c707_0 = scale0 * 0.70710678118654752f;
      const float c707_1 = scale1 * 0.70710678118654752f;
      const float chalf0 = scale0 * 0.5f;
      const float chalf1 = scale1 * 0.5f;
      gs0 = 0.f; gs1 = 0.f;
#pragma unroll
      for (int t = 0; t < 2; ++t)
#pragma unroll
        for (int e = 0; e < 16; ++e) {
          const float g0 = gelu_s(acc[t][0][e], c707_0, chalf0);
          acc[t][0][e] = g0; gs0 += g0;
          const float g1 = gelu_s(acc[t][1][e], c707_1, chalf1);
          acc[t][1][e] = g1; gs1 += g1;
        }
      gs0 += __shfl_xor(gs0, 32);
      gs1 += __shfl_xor(gs1, 32);
    }
    if (hasC) {
#pragma unroll
      for (int u = 8; u < 16; ++u) {
        const int s2 = pn * 64 + u * 4 + l4;
        const bf16x8 bb = *(const bf16x8*)(vph + ((size_t)s2 * 128 + pc * 16 + l15) * 8);
        const char* arow = smem + (size_t)s2 * 1024;
#pragma unroll
        for (int qs = 0; qs < 4; ++qs) {
          const int q = qs * 16 + l15;
          const bf16x8 aa = *(const bf16x8*)(arow + (q ^ (s2 & 7)) * 16);
          pv[qs] = __builtin_amdgcn_mfma_f32_16x16x32_bf16(aa, bb, pv[qs], 0, 0, 0);
        }
      }
    }
    if (i + 1 < 4) {  // stage Q(i+1) (Q(i) reads finished in segA)
      const float* xq = x + ((size_t)(b * 2048 + t0base + (i + 1) * 64)) * 1024 + h * 128;
      const int r = tid >> 4, kc = tid & 15;
      const float* sp = xq + (size_t)r * 1024 + kc * 8;
      const float4 f0 = *(const float4*)sp;
      const float4 f1 = *(const float4*)(sp + 4);
      const float fv[8] = {f0.x, f0.y, f0.z, f0.w, f1.x, f1.y, f1.z, f1.w};
      bf16x8 hv; float lv[8];
#pragma unroll
      for (int e = 0; e < 8; ++e) {
        const __bf16 hb = (__bf16)fv[e];
        hv[e] = hb;
        lv[e] = (fv[e] - (float)hb) * 1024.0f;
      }
      const int g = kc * 64 + (r ^ ((kc >> 1) & 7));
      *(bf16x8*)(smem + QHI_OFF + g * 16) = hv;
      unsigned int w0 = pack_fp8_pair<false>(lv[0], lv[1], 0u);
      w0 = pack_fp8_pair<true>(lv[2], lv[3], w0);
      unsigned int w1 = pack_fp8_pair<false>(lv[4], lv[5], 0u);
      w1 = pack_fp8_pair<true>(lv[6], lv[7], w1);
      *(uint2*)(smem + QLO_OFF + g * 8) = make_uint2(w0, w1);
    }
    __syncthreads();

    // ===== segB2: publish gs ∥ out atomics for tile i-1 =====
    if (hasP) red[wave * 64 + lane] = hi ? gs1 : gs0;
    if (hasC) {
      const int t0c = t0base + (i - 1) * 64;
      float* ob = out + ((size_t)(b * 2048 + t0c)) * 1024 + h * 128 + pc * 16 + l15;
#pragma unroll
      for (int qs = 0; qs < 4; ++qs)
#pragma unroll
        for (int j = 0; j < 4; ++j)
          atomicAdd(ob + (size_t)(qs * 16 + l4 * 4 + j) * 1024, pv[qs][j]);
    }
    __syncthreads();

    // ===== segC: mean + mask + pack(i) -> S =====
    if (hasP) {
      float mean0 = 0.f, mean1 = 0.f;
#pragma unroll
      for (int w = 0; w < 16; ++w) {
        mean0 += red[w * 64 + l31];
        mean1 += red[w * 64 + 32 + l31];
      }
      mean0 *= (1.0f / 1024.0f);
      mean1 *= (1.0f / 1024.0f);
#pragma unroll
      for (int t = 0; t < 2; ++t) {
#pragma unroll
        for (int qt = 0; qt < 2; ++qt) {
          const float mn = qt ? mean1 : mean0;
          const int q = qt * 32 + l31;
#pragma unroll
          for (int gi = 0; gi < 4; ++gi) {
            float g0 = acc[t][qt][4 * gi + 0]; g0 = (g0 > mn) ? g0 : 0.f;
            float g1 = acc[t][qt][4 * gi + 1]; g1 = (g1 > mn) ? g1 : 0.f;
            float g2 = acc[t][qt][4 * gi + 2]; g2 = (g2 > mn) ? g2 : 0.f;
            float g3 = acc[t][qt][4 * gi + 3]; g3 = (g3 > mn) ? g3 : 0.f;
            uint2 pk;
            pk.x = (unsigned)bfbits((__bf16)g0) | ((unsigned)bfbits((__bf16)g1) << 16);
            pk.y = (unsigned)bfbits((__bf16)g2) | ((unsigned)bfbits((__bf16)g3) << 16);
            const int ng = wave * 8 + t * 4 + gi;
            const int swz = (t * 4 + gi) & 7;           // = ng & 7
            *(uint2*)(smem + (ng * 64 + (q ^ swz)) * 16 + hi * 8) = pk;
          }
        }
      }
    }
    __syncthreads();
  }
}

// ---------------- launch ----------------

extern "C" void kernel_launch(void* const* d_in, const int* in_sizes, int n_in,
                              void* d_out, int out_size, void* d_ws, size_t ws_size,
                              hipStream_t stream) {
  const float* x   = (const float*)d_in[0];  // [4][2048][1024]
  const float* key = (const float*)d_in[1];  // [8][1024][128]
  const float* val = (const float*)d_in[2];  // [8][1024][128]
  float* out = (float*)d_out;                // [4][2048][1024]

  if (ws_size < (size_t)6 * 1024 * 1024) return;  // need 6 MB scratch

  unsigned short* k_hi = (unsigned short*)d_ws;   // 1M bf16 (2 MB)
  unsigned short* k_lo = k_hi + 1048576;          // 1M bf16
  unsigned short* v_pk = k_lo + 1048576;          // 1M bf16 (frag-packed V)

  (void)hipMemsetAsync(d_out, 0, (size_t)out_size * sizeof(float), stream);
  prep_kv<<<dim3(1024), dim3(256), 0, stream>>>(key, val, k_hi, k_lo, v_pk);
  fused_mhk<<<dim3(256), dim3(1024), SMEMSZ, stream>>>(x, k_hi, k_lo, v_pk, out);
}

// Round 8
// 121.004 us; speedup vs baseline: 2.9613x; 2.9613x over previous
//
#include <hip/hip_runtime.h>
#include <cstdint>
#include <cmath>

// ---------------------------------------------------------------------------
// MHKPattLayer fused kernel for MI355X (gfx950) — round 8
//   QBLK=64, 1024 threads (16 waves), grid 1024, 1 tile/block.
//   QK: 3-pass bf16-split, K staged in LDS via global_load_lds (2-phase
//       double-buffer, T3 minimal recipe). Q-hi bf16 + Q-lo fp8 in LDS.
//   GELU exact (A&S 7.1.28) + mean-mask in f32, pack S bf16 into the dead
//   K-buffer region, PV on 8 waves with 32x32 tiles (R4-proven).
// B=4, T=2048, C=1024, H=8, N=1024, Dk=Dv=128
// ---------------------------------------------------------------------------

typedef __bf16 bf16x8 __attribute__((ext_vector_type(8)));
typedef float  f32x16 __attribute__((ext_vector_type(16)));
typedef float  f32x4  __attribute__((ext_vector_type(4)));
typedef unsigned short u16x8 __attribute__((ext_vector_type(8)));

#if defined(__has_builtin)
#if __has_builtin(__builtin_amdgcn_cvt_pk_f32_fp8) && __has_builtin(__builtin_amdgcn_cvt_pk_fp8_f32)
#define HW_FP8 1
#endif
#endif
#ifndef HW_FP8
#define HW_FP8 0
#endif

__device__ __forceinline__ unsigned short bfbits(__bf16 b) {
  return __builtin_bit_cast(unsigned short, b);
}

// async global->LDS, 16B per lane: dest = uniform lds base + lane*16,
// source = per-lane global pointer. Size must be a literal.
__device__ __forceinline__ void gload_lds16(const void* g, void* l) {
  __builtin_amdgcn_global_load_lds(
      (const __attribute__((address_space(1))) void*)g,
      (__attribute__((address_space(3))) void*)l, 16, 0, 0);
}

// ---- fp8 e4m3 storage of q_lo*1024 (all-normal range; tiny values -> 0) ----
__device__ __forceinline__ unsigned int enc_fp8_1(float f) {
  unsigned int u = __float_as_uint(f);
  unsigned int s = u >> 31;
  u &= 0x7FFFFFFFu;
  unsigned int r = (u + 0x7FFFFu + ((u >> 20) & 1u)) >> 20;
  unsigned int mag = (r >= 968u) ? (r - 960u) : 0u;
  if (mag > 127u) mag = 127u;
  return (s << 7) | mag;
}

template <bool WORD>
__device__ __forceinline__ unsigned int pack_fp8_pair(float a, float b,
                                                      unsigned int old) {
#if HW_FP8
  return (unsigned int)__builtin_amdgcn_cvt_pk_fp8_f32(a, b, (int)old, WORD);
#else
  const unsigned int pk = enc_fp8_1(a) | (enc_fp8_1(b) << 8);
  return WORD ? ((old & 0x0000FFFFu) | (pk << 16))
              : ((old & 0xFFFF0000u) | pk);
#endif
}

__device__ __forceinline__ unsigned short dec_fp8_1(unsigned int b) {
  const unsigned int t = b & 0x7Fu;
  unsigned int v = (t << 4) + 14080u;
  v |= (b & 0x80u) << 8;
  return (t >= 16u) ? (unsigned short)v : (unsigned short)0;
}

__device__ __forceinline__ bf16x8 dec_qlo(uint2 lo) {
#if HW_FP8
  const float S = 1.0f / 1024.0f;
  auto p0 = __builtin_amdgcn_cvt_pk_f32_fp8((int)lo.x, false);
  auto p1 = __builtin_amdgcn_cvt_pk_f32_fp8((int)lo.x, true);
  auto p2 = __builtin_amdgcn_cvt_pk_f32_fp8((int)lo.y, false);
  auto p3 = __builtin_amdgcn_cvt_pk_f32_fp8((int)lo.y, true);
  unsigned int w0, w1, w2, w3;
  asm("v_cvt_pk_bf16_f32 %0, %1, %2" : "=v"(w0) : "v"(p0[0] * S), "v"(p0[1] * S));
  asm("v_cvt_pk_bf16_f32 %0, %1, %2" : "=v"(w1) : "v"(p1[0] * S), "v"(p1[1] * S));
  asm("v_cvt_pk_bf16_f32 %0, %1, %2" : "=v"(w2) : "v"(p2[0] * S), "v"(p2[1] * S));
  asm("v_cvt_pk_bf16_f32 %0, %1, %2" : "=v"(w3) : "v"(p3[0] * S), "v"(p3[1] * S));
  uint4 uu = make_uint4(w0, w1, w2, w3);
  return __builtin_bit_cast(bf16x8, uu);
#else
  unsigned short r0 = dec_fp8_1(lo.x & 0xFFu);
  unsigned short r1 = dec_fp8_1((lo.x >> 8) & 0xFFu);
  unsigned short r2 = dec_fp8_1((lo.x >> 16) & 0xFFu);
  unsigned short r3 = dec_fp8_1(lo.x >> 24);
  unsigned short r4 = dec_fp8_1(lo.y & 0xFFu);
  unsigned short r5 = dec_fp8_1((lo.y >> 8) & 0xFFu);
  unsigned short r6 = dec_fp8_1((lo.y >> 16) & 0xFFu);
  unsigned short r7 = dec_fp8_1(lo.y >> 24);
  uint4 uu = make_uint4((unsigned)r0 | ((unsigned)r1 << 16),
                        (unsigned)r2 | ((unsigned)r3 << 16),
                        (unsigned)r4 | ((unsigned)r5 << 16),
                        (unsigned)r6 | ((unsigned)r7 << 16));
  return __builtin_bit_cast(bf16x8, uu);
#endif
}

// exact GELU, scale pre-folded (A&S 7.1.28, |eps|<=3e-7)
__device__ __forceinline__ float gelu_s(float raw, float c707, float chalf) {
  const float s = raw * c707;
  const float a = fabsf(s);
  float u = fmaf(a, 4.30638e-5f, 2.765672e-4f);
  u = fmaf(u, a, 1.520143e-4f);
  u = fmaf(u, a, 9.2705272e-3f);
  u = fmaf(u, a, 4.22820123e-2f);
  u = fmaf(u, a, 7.05230784e-2f);
  u = fmaf(u, a, 1.0f);
  const float r  = __builtin_amdgcn_rcpf(u);
  const float r2 = r * r;
  const float r4 = r2 * r2;
  const float r8 = r4 * r4;
  const float er = copysignf(1.0f - r8 * r8, s);
  const float hf = raw * chalf;
  return fmaf(hf, er, hf);
}

// ---------------- prep kernel ----------------
// first 65536 threads: K -> hi/lo bf16 step-packed [h][s=8][n=1024][e=16]
//   element e of step s = key[h][n][s*16+e]   (16 shorts contiguous per (s,n))
// next 131072 threads: V -> bf16 frag-packed [h][s2=128][v=128][e=8]
__global__ void prep_kv(const float* __restrict__ key,
                        const float* __restrict__ val,
                        unsigned short* __restrict__ kh,
                        unsigned short* __restrict__ kl,
                        unsigned short* __restrict__ vp) {
  const int gid = blockIdx.x * 256 + threadIdx.x;   // 0..196607
  if (gid < 65536) {
    const int h = gid >> 13;
    const int s = (gid >> 10) & 7;
    const int n = gid & 1023;
    const float* src = key + ((size_t)(h << 10) + n) * 128 + s * 16;
    float fv[16];
#pragma unroll
    for (int j = 0; j < 4; ++j) {
      const float4 f = *(const float4*)(src + j * 4);
      fv[j * 4 + 0] = f.x; fv[j * 4 + 1] = f.y;
      fv[j * 4 + 2] = f.z; fv[j * 4 + 3] = f.w;
    }
    u16x8 hv0, hv1, lv0, lv1;
#pragma unroll
    for (int e = 0; e < 8; ++e) {
      const __bf16 hb0 = (__bf16)fv[e];
      hv0[e] = bfbits(hb0);
      lv0[e] = bfbits((__bf16)(fv[e] - (float)hb0));
      const __bf16 hb1 = (__bf16)fv[8 + e];
      hv1[e] = bfbits(hb1);
      lv1[e] = bfbits((__bf16)(fv[8 + e] - (float)hb1));
    }
    const size_t o = ((size_t)(h * 8 + s) * 1024 + n) * 16;
    *(u16x8*)(kh + o) = hv0;  *(u16x8*)(kh + o + 8) = hv1;
    *(u16x8*)(kl + o) = lv0;  *(u16x8*)(kl + o + 8) = lv1;
  } else {
    const int tid = gid - 65536;
    const int h   = tid >> 14;
    const int s2  = (tid >> 7) & 127;
    const int v   = tid & 127;
    const float* src = val + ((size_t)(h << 10) + s2 * 8) * 128 + v;
    u16x8 ov;
#pragma unroll
    for (int e = 0; e < 8; ++e) ov[e] = bfbits((__bf16)src[(size_t)e * 128]);
    *(u16x8*)(vp + ((size_t)(h * 128 + s2) * 128 + v) * 8) = ov;
  }
}

// ---------------- fused kernel ----------------
// LDS: [0,131072)      QK phase: K dbuf 2 x 64KB { hi [n][16e] 32KB, lo +32768 }
//                      PV phase: S granules slot=(ng*64+(q^(ng&7)))*16
//      [131072,147456) Q-hi bf16 granules g=kc*64+(r^((kc>>1)&7)), 16B each
//      [147456,155648) Q-lo fp8 granules, 8B each
//      [155648,159744) red [16][64] f32
#define QHI_OFF 131072
#define QLO_OFF 147456
#define RED_OFF 155648
#define SMEMSZ  159744

__global__ __launch_bounds__(1024, 4) void fused_mhk(
    const float* __restrict__ x,
    const unsigned short* __restrict__ k_hi,
    const unsigned short* __restrict__ k_lo,
    const unsigned short* __restrict__ v_pk,
    float* __restrict__ out)
{
  extern __shared__ char smem[];
  const int tid  = threadIdx.x;
  const int wave = tid >> 6;
  const int lane = tid & 63;
  const int l31  = lane & 31;
  const int hi   = lane >> 5;

  const int bid = blockIdx.x;
  const int h   = bid & 7;        // head fixed per XCD slot
  const int g8  = bid >> 3;
  const int b   = g8 & 3;
  const int tt  = g8 >> 2;
  const int t0  = tt * 64;

  const unsigned short* kh2 = k_hi + (size_t)h * 131072;  // [s][n][16]
  const unsigned short* kl2 = k_lo + (size_t)h * 131072;
  float* red = (float*)(smem + RED_OFF);

  // ---- Phase 0: stage Q tile (hi bf16 + lo fp8) and async-stage K[0]
  {
    const float* xq = x + ((size_t)(b * 2048 + t0)) * 1024 + h * 128;
    const int r = tid >> 4, kc = tid & 15;
    const float* sp = xq + (size_t)r * 1024 + kc * 8;
    const float4 f0 = *(const float4*)sp;
    const float4 f1 = *(const float4*)(sp + 4);
    const float fv[8] = {f0.x, f0.y, f0.z, f0.w, f1.x, f1.y, f1.z, f1.w};
    bf16x8 hv; float lv[8];
#pragma unroll
    for (int e = 0; e < 8; ++e) {
      const __bf16 hb = (__bf16)fv[e];
      hv[e] = hb;
      lv[e] = (fv[e] - (float)hb) * 1024.0f;
    }
    const int g = kc * 64 + (r ^ ((kc >> 1) & 7));
    *(bf16x8*)(smem + QHI_OFF + g * 16) = hv;
    unsigned int w0 = pack_fp8_pair<false>(lv[0], lv[1], 0u);
    w0 = pack_fp8_pair<true>(lv[2], lv[3], w0);
    unsigned int w1 = pack_fp8_pair<false>(lv[4], lv[5], 0u);
    w1 = pack_fp8_pair<true>(lv[6], lv[7], w1);
    *(uint2*)(smem + QLO_OFF + g * 8) = make_uint2(w0, w1);
  }
  {
    const unsigned short* sh = kh2 + wave * 1024 + lane * 8;
    const unsigned short* sl = kl2 + wave * 1024 + lane * 8;
    gload_lds16(sh,       smem + wave * 2048);
    gload_lds16(sh + 512, smem + wave * 2048 + 1024);
    gload_lds16(sl,       smem + 32768 + wave * 2048);
    gload_lds16(sl + 512, smem + 32768 + wave * 2048 + 1024);
  }
  __syncthreads();

  // ---- Phase 1: QK^T, 2-phase staged. acc[t][qt]: lane q = qt*32+l31,
  //      n = wave*64 + t*32 + crow(r,hi)
  f32x16 acc[2][2];
#pragma unroll
  for (int t = 0; t < 2; ++t)
#pragma unroll
    for (int qt = 0; qt < 2; ++qt)
#pragma unroll
      for (int e = 0; e < 16; ++e) acc[t][qt][e] = 0.f;

#pragma unroll
  for (int s = 0; s < 8; ++s) {
    // stage K[s+1] into the other buffer (loads fly across the whole step)
    if (s < 7) {
      char* nxt = smem + ((s + 1) & 1) * 65536;
      const unsigned short* sh = kh2 + (s + 1) * 16384 + wave * 1024 + lane * 8;
      const unsigned short* sl = kl2 + (s + 1) * 16384 + wave * 1024 + lane * 8;
      gload_lds16(sh,       nxt + wave * 2048);
      gload_lds16(sh + 512, nxt + wave * 2048 + 1024);
      gload_lds16(sl,       nxt + 32768 + wave * 2048);
      gload_lds16(sl + 512, nxt + 32768 + wave * 2048 + 1024);
    }
    const char* cur = smem + (s & 1) * 65536;
    // Q fragments
    const int gx0 = (2 * s + hi) * 64 + (l31 ^ s);
    const int gx1 = (2 * s + hi) * 64 + ((32 + l31) ^ s);
    const bf16x8 bqh0 = *(const bf16x8*)(smem + QHI_OFF + gx0 * 16);
    const bf16x8 bqh1 = *(const bf16x8*)(smem + QHI_OFF + gx1 * 16);
    const bf16x8 bql0 = dec_qlo(*(const uint2*)(smem + QLO_OFF + gx0 * 8));
    const bf16x8 bql1 = dec_qlo(*(const uint2*)(smem + QLO_OFF + gx1 * 8));
    // K fragments from LDS
    const int na = wave * 64 + l31;
    const bf16x8 ah0 = *(const bf16x8*)(cur + na * 32 + hi * 16);
    const bf16x8 ah1 = *(const bf16x8*)(cur + (na + 32) * 32 + hi * 16);
    const bf16x8 al0 = *(const bf16x8*)(cur + 32768 + na * 32 + hi * 16);
    const bf16x8 al1 = *(const bf16x8*)(cur + 32768 + (na + 32) * 32 + hi * 16);

    acc[0][0] = __builtin_amdgcn_mfma_f32_32x32x16_bf16(ah0, bqh0, acc[0][0], 0, 0, 0);
    acc[0][1] = __builtin_amdgcn_mfma_f32_32x32x16_bf16(ah0, bqh1, acc[0][1], 0, 0, 0);
    acc[0][0] = __builtin_amdgcn_mfma_f32_32x32x16_bf16(ah0, bql0, acc[0][0], 0, 0, 0);
    acc[0][1] = __builtin_amdgcn_mfma_f32_32x32x16_bf16(ah0, bql1, acc[0][1], 0, 0, 0);
    acc[0][0] = __builtin_amdgcn_mfma_f32_32x32x16_bf16(al0, bqh0, acc[0][0], 0, 0, 0);
    acc[0][1] = __builtin_amdgcn_mfma_f32_32x32x16_bf16(al0, bqh1, acc[0][1], 0, 0, 0);
    acc[1][0] = __builtin_amdgcn_mfma_f32_32x32x16_bf16(ah1, bqh0, acc[1][0], 0, 0, 0);
    acc[1][1] = __builtin_amdgcn_mfma_f32_32x32x16_bf16(ah1, bqh1, acc[1][1], 0, 0, 0);
    acc[1][0] = __builtin_amdgcn_mfma_f32_32x32x16_bf16(ah1, bql0, acc[1][0], 0, 0, 0);
    acc[1][1] = __builtin_amdgcn_mfma_f32_32x32x16_bf16(ah1, bql1, acc[1][1], 0, 0, 0);
    acc[1][0] = __builtin_amdgcn_mfma_f32_32x32x16_bf16(al1, bqh0, acc[1][0], 0, 0, 0);
    acc[1][1] = __builtin_amdgcn_mfma_f32_32x32x16_bf16(al1, bqh1, acc[1][1], 0, 0, 0);

    __syncthreads();  // drains vmcnt (stage s+1 landed) + lgkm; frees cur
  }

  // ---- Phase 2: l2-norm -> scale -> GELU -> mean (per q-row)
  float ss0 = 0.f, ss1 = 0.f;
#pragma unroll
  for (int t = 0; t < 2; ++t)
#pragma unroll
    for (int e = 0; e < 16; ++e) {
      ss0 += acc[t][0][e] * acc[t][0][e];
      ss1 += acc[t][1][e] * acc[t][1][e];
    }
  ss0 += __shfl_xor(ss0, 32);
  ss1 += __shfl_xor(ss1, 32);
  red[wave * 64 + lane] = hi ? ss1 : ss0;
  __syncthreads();
  float sum0 = 0.f, sum1 = 0.f;
#pragma unroll
  for (int w = 0; w < 16; ++w) {
    sum0 += red[w * 64 + l31];
    sum1 += red[w * 64 + 32 + l31];
  }
  const float scale0 = 32.0f / fmaxf(sqrtf(sum0), 1e-8f);
  const float scale1 = 32.0f / fmaxf(sqrtf(sum1), 1e-8f);
  const float c707_0 = scale0 * 0.70710678118654752f;
  const float c707_1 = scale1 * 0.70710678118654752f;
  const float chalf0 = scale0 * 0.5f;
  const float chalf1 = scale1 * 0.5f;

  float gs0 = 0.f, gs1 = 0.f;
#pragma unroll
  for (int t = 0; t < 2; ++t)
#pragma unroll
    for (int e = 0; e < 16; ++e) {
      const float g0 = gelu_s(acc[t][0][e], c707_0, chalf0);
      acc[t][0][e] = g0; gs0 += g0;
      const float g1 = gelu_s(acc[t][1][e], c707_1, chalf1);
      acc[t][1][e] = g1; gs1 += g1;
    }
  gs0 += __shfl_xor(gs0, 32);
  gs1 += __shfl_xor(gs1, 32);
  __syncthreads();                    // all red reads done before rewrite
  red[wave * 64 + lane] = hi ? gs1 : gs0;
  __syncthreads();
  float mean0 = 0.f, mean1 = 0.f;
#pragma unroll
  for (int w = 0; w < 16; ++w) {
    mean0 += red[w * 64 + l31];
    mean1 += red[w * 64 + 32 + l31];
  }
  mean0 *= (1.0f / 1024.0f);
  mean1 *= (1.0f / 1024.0f);

  // ---- Phase 3: mask (strict >) + bf16 pack -> S granules (over dead K bufs)
#pragma unroll
  for (int t = 0; t < 2; ++t) {
#pragma unroll
    for (int qt = 0; qt < 2; ++qt) {
      const float mn = qt ? mean1 : mean0;
      const int q = qt * 32 + l31;
#pragma unroll
      for (int gi = 0; gi < 4; ++gi) {
        float g0 = acc[t][qt][4 * gi + 0]; g0 = (g0 > mn) ? g0 : 0.f;
        float g1 = acc[t][qt][4 * gi + 1]; g1 = (g1 > mn) ? g1 : 0.f;
        float g2 = acc[t][qt][4 * gi + 2]; g2 = (g2 > mn) ? g2 : 0.f;
        float g3 = acc[t][qt][4 * gi + 3]; g3 = (g3 > mn) ? g3 : 0.f;
        uint2 pk;
        pk.x = (unsigned)bfbits((__bf16)g0) | ((unsigned)bfbits((__bf16)g1) << 16);
        pk.y = (unsigned)bfbits((__bf16)g2) | ((unsigned)bfbits((__bf16)g3) << 16);
        const int ng = wave * 8 + t * 4 + gi;
        const int swz = (t * 4 + gi) & 7;               // = ng & 7
        *(uint2*)(smem + (ng * 64 + (q ^ swz)) * 16 + hi * 8) = pk;
      }
    }
  }
  __syncthreads();

  // ---- Phase 4: PV on 8 waves, 32x32 tiles (R4-proven)
  if (wave >= 8) return;
  const int qt2 = wave >> 2;
  const int vt  = wave & 3;
  const int q   = qt2 * 32 + l31;

  f32x16 o;
#pragma unroll
  for (int e = 0; e < 16; ++e) o[e] = 0.f;

  const unsigned short* vb = v_pk + (size_t)h * 131072 + (size_t)hi * 1024 +
                             (size_t)(vt * 32 + l31) * 8;
#pragma unroll 8
  for (int ks = 0; ks < 64; ++ks) {
    const int ng = 2 * ks + hi;
    const bf16x8 aa = *(const bf16x8*)(smem + (ng * 64 + (q ^ (ng & 7))) * 16);
    const bf16x8 bb = *(const bf16x8*)(vb + (size_t)ks * 2048);
    o = __builtin_amdgcn_mfma_f32_32x32x16_bf16(aa, bb, o, 0, 0, 0);
  }

  float* op = out + ((size_t)(b * 2048 + t0 + qt2 * 32)) * 1024 +
              h * 128 + vt * 32 + l31;
#pragma unroll
  for (int r = 0; r < 16; ++r) {
    const int qr = (r & 3) + 8 * (r >> 2) + 4 * hi;
    op[(size_t)qr * 1024] = o[r];
  }
}

// ---------------- launch ----------------

extern "C" void kernel_launch(void* const* d_in, const int* in_sizes, int n_in,
                              void* d_out, int out_size, void* d_ws, size_t ws_size,
                              hipStream_t stream) {
  const float* x   = (const float*)d_in[0];  // [4][2048][1024]
  const float* key = (const float*)d_in[1];  // [8][1024][128]
  const float* val = (const float*)d_in[2];  // [8][1024][128]
  float* out = (float*)d_out;                // [4][2048][1024]

  if (ws_size < (size_t)6 * 1024 * 1024) return;  // need 6 MB scratch

  unsigned short* k_hi = (unsigned short*)d_ws;   // 1M shorts (2 MB)
  unsigned short* k_lo = k_hi + 1048576;          // 1M shorts
  unsigned short* v_pk = k_lo + 1048576;          // 1M shorts (frag-packed V)

  prep_kv<<<dim3(768), dim3(256), 0, stream>>>(key, val, k_hi, k_lo, v_pk);
  fused_mhk<<<dim3(1024), dim3(1024), SMEMSZ, stream>>>(x, k_hi, k_lo, v_pk, out);
}

// Round 9
// 113.147 us; speedup vs baseline: 3.1670x; 1.0694x over previous
//
#include <hip/hip_runtime.h>
#include <cstdint>
#include <cmath>

// ---------------------------------------------------------------------------
// MHKPattLayer fused kernel for MI355X (gfx950) — round 9
//   QBLK=64, 1024 threads (16 waves), grid 1024, 1 tile/block.
//   QK: 3-pass bf16-split, K staged via global_load_lds into PER-WAVE-PRIVATE
//       LDS regions -> BARRIER-FREE inner loop with counted s_waitcnt vmcnt(4)
//       (T3+T4), setprio around MFMA cluster (T5).
//   GELU exact (A&S 7.1.28) in packed float2 (v_pk_fma_f32 path).
//   PV on 8 waves, 32x32 tiles, V prefetched 1 step ahead (R4-proven layout).
// B=4, T=2048, C=1024, H=8, N=1024, Dk=Dv=128
// ---------------------------------------------------------------------------

typedef __bf16 bf16x8 __attribute__((ext_vector_type(8)));
typedef float  f32x16 __attribute__((ext_vector_type(16)));
typedef float  f32x2  __attribute__((ext_vector_type(2)));
typedef unsigned short u16x8 __attribute__((ext_vector_type(8)));

#if defined(__has_builtin)
#if __has_builtin(__builtin_amdgcn_cvt_pk_f32_fp8) && __has_builtin(__builtin_amdgcn_cvt_pk_fp8_f32)
#define HW_FP8 1
#endif
#endif
#ifndef HW_FP8
#define HW_FP8 0
#endif

__device__ __forceinline__ unsigned short bfbits(__bf16 b) {
  return __builtin_bit_cast(unsigned short, b);
}

// async global->LDS, 16B per lane: dest = uniform lds base + lane*16.
__device__ __forceinline__ void gload_lds16(const void* g, void* l) {
  __builtin_amdgcn_global_load_lds(
      (const __attribute__((address_space(1))) void*)g,
      (__attribute__((address_space(3))) void*)l, 16, 0, 0);
}

// ---- fp8 e4m3 storage of q_lo*1024 (all-normal range; tiny values -> 0) ----
__device__ __forceinline__ unsigned int enc_fp8_1(float f) {
  unsigned int u = __float_as_uint(f);
  unsigned int s = u >> 31;
  u &= 0x7FFFFFFFu;
  unsigned int r = (u + 0x7FFFFu + ((u >> 20) & 1u)) >> 20;
  unsigned int mag = (r >= 968u) ? (r - 960u) : 0u;
  if (mag > 127u) mag = 127u;
  return (s << 7) | mag;
}

template <bool WORD>
__device__ __forceinline__ unsigned int pack_fp8_pair(float a, float b,
                                                      unsigned int old) {
#if HW_FP8
  return (unsigned int)__builtin_amdgcn_cvt_pk_fp8_f32(a, b, (int)old, WORD);
#else
  const unsigned int pk = enc_fp8_1(a) | (enc_fp8_1(b) << 8);
  return WORD ? ((old & 0x0000FFFFu) | (pk << 16))
              : ((old & 0xFFFF0000u) | pk);
#endif
}

__device__ __forceinline__ unsigned short dec_fp8_1(unsigned int b) {
  const unsigned int t = b & 0x7Fu;
  unsigned int v = (t << 4) + 14080u;
  v |= (b & 0x80u) << 8;
  return (t >= 16u) ? (unsigned short)v : (unsigned short)0;
}

__device__ __forceinline__ bf16x8 dec_qlo(uint2 lo) {
#if HW_FP8
  const float S = 1.0f / 1024.0f;
  auto p0 = __builtin_amdgcn_cvt_pk_f32_fp8((int)lo.x, false);
  auto p1 = __builtin_amdgcn_cvt_pk_f32_fp8((int)lo.x, true);
  auto p2 = __builtin_amdgcn_cvt_pk_f32_fp8((int)lo.y, false);
  auto p3 = __builtin_amdgcn_cvt_pk_f32_fp8((int)lo.y, true);
  unsigned int w0, w1, w2, w3;
  asm("v_cvt_pk_bf16_f32 %0, %1, %2" : "=v"(w0) : "v"(p0[0] * S), "v"(p0[1] * S));
  asm("v_cvt_pk_bf16_f32 %0, %1, %2" : "=v"(w1) : "v"(p1[0] * S), "v"(p1[1] * S));
  asm("v_cvt_pk_bf16_f32 %0, %1, %2" : "=v"(w2) : "v"(p2[0] * S), "v"(p2[1] * S));
  asm("v_cvt_pk_bf16_f32 %0, %1, %2" : "=v"(w3) : "v"(p3[0] * S), "v"(p3[1] * S));
  uint4 uu = make_uint4(w0, w1, w2, w3);
  return __builtin_bit_cast(bf16x8, uu);
#else
  unsigned short r0 = dec_fp8_1(lo.x & 0xFFu);
  unsigned short r1 = dec_fp8_1((lo.x >> 8) & 0xFFu);
  unsigned short r2 = dec_fp8_1((lo.x >> 16) & 0xFFu);
  unsigned short r3 = dec_fp8_1(lo.x >> 24);
  unsigned short r4 = dec_fp8_1(lo.y & 0xFFu);
  unsigned short r5 = dec_fp8_1((lo.y >> 8) & 0xFFu);
  unsigned short r6 = dec_fp8_1((lo.y >> 16) & 0xFFu);
  unsigned short r7 = dec_fp8_1(lo.y >> 24);
  uint4 uu = make_uint4((unsigned)r0 | ((unsigned)r1 << 16),
                        (unsigned)r2 | ((unsigned)r3 << 16),
                        (unsigned)r4 | ((unsigned)r5 << 16),
                        (unsigned)r6 | ((unsigned)r7 << 16));
  return __builtin_bit_cast(bf16x8, uu);
#endif
}

// exact GELU on a float2, scale pre-folded (A&S 7.1.28, |eps|<=3e-7).
// Vector ops -> v_pk_fma_f32 / v_pk_mul_f32 on gfx950.
__device__ __forceinline__ f32x2 gelu2(f32x2 raw, float c707, float chalf) {
  const f32x2 s = raw * c707;
  const f32x2 a = __builtin_elementwise_abs(s);
  f32x2 u = a * 4.30638e-5f + 2.765672e-4f;
  u = __builtin_elementwise_fma(u, a, (f32x2)1.520143e-4f);
  u = __builtin_elementwise_fma(u, a, (f32x2)9.2705272e-3f);
  u = __builtin_elementwise_fma(u, a, (f32x2)4.22820123e-2f);
  u = __builtin_elementwise_fma(u, a, (f32x2)7.05230784e-2f);
  u = __builtin_elementwise_fma(u, a, (f32x2)1.0f);
  f32x2 r;
  r.x = __builtin_amdgcn_rcpf(u.x);
  r.y = __builtin_amdgcn_rcpf(u.y);
  const f32x2 r2 = r * r;
  const f32x2 r4 = r2 * r2;
  const f32x2 r8 = r4 * r4;
  const f32x2 er = __builtin_elementwise_copysign((f32x2)1.0f - r8 * r8, s);
  const f32x2 hf = raw * chalf;
  return __builtin_elementwise_fma(hf, er, hf);
}

// ---------------- prep kernel ----------------
// first 65536 threads: K -> hi/lo bf16 step-packed [h][s=8][n=1024][e=16]
// next 131072 threads: V -> bf16 frag-packed [h][s2=128][v=128][e=8]
__global__ void prep_kv(const float* __restrict__ key,
                        const float* __restrict__ val,
                        unsigned short* __restrict__ kh,
                        unsigned short* __restrict__ kl,
                        unsigned short* __restrict__ vp) {
  const int gid = blockIdx.x * 256 + threadIdx.x;   // 0..196607
  if (gid < 65536) {
    const int h = gid >> 13;
    const int s = (gid >> 10) & 7;
    const int n = gid & 1023;
    const float* src = key + ((size_t)(h << 10) + n) * 128 + s * 16;
    float fv[16];
#pragma unroll
    for (int j = 0; j < 4; ++j) {
      const float4 f = *(const float4*)(src + j * 4);
      fv[j * 4 + 0] = f.x; fv[j * 4 + 1] = f.y;
      fv[j * 4 + 2] = f.z; fv[j * 4 + 3] = f.w;
    }
    u16x8 hv0, hv1, lv0, lv1;
#pragma unroll
    for (int e = 0; e < 8; ++e) {
      const __bf16 hb0 = (__bf16)fv[e];
      hv0[e] = bfbits(hb0);
      lv0[e] = bfbits((__bf16)(fv[e] - (float)hb0));
      const __bf16 hb1 = (__bf16)fv[8 + e];
      hv1[e] = bfbits(hb1);
      lv1[e] = bfbits((__bf16)(fv[8 + e] - (float)hb1));
    }
    const size_t o = ((size_t)(h * 8 + s) * 1024 + n) * 16;
    *(u16x8*)(kh + o) = hv0;  *(u16x8*)(kh + o + 8) = hv1;
    *(u16x8*)(kl + o) = lv0;  *(u16x8*)(kl + o + 8) = lv1;
  } else {
    const int tid = gid - 65536;
    const int h   = tid >> 14;
    const int s2  = (tid >> 7) & 127;
    const int v   = tid & 127;
    const float* src = val + ((size_t)(h << 10) + s2 * 8) * 128 + v;
    u16x8 ov;
#pragma unroll
    for (int e = 0; e < 8; ++e) ov[e] = bfbits((__bf16)src[(size_t)e * 128]);
    *(u16x8*)(vp + ((size_t)(h * 128 + s2) * 128 + v) * 8) = ov;
  }
}

// ---------------- fused kernel ----------------
// LDS: [0,131072)      QK phase: K dbuf 2 x 64KB { hi [n][16e] 32KB, lo +32768 }
//                      (wave w's region = bytes [w*2048, w*2048+2048) per half)
//                      PV phase: S granules slot=(ng*64+(q^(ng&7)))*16
//      [131072,147456) Q-hi bf16 granules g=kc*64+(r^((kc>>1)&7)), 16B each
//      [147456,155648) Q-lo fp8 granules, 8B each
//      [155648,159744) red [16][64] f32
#define QHI_OFF 131072
#define QLO_OFF 147456
#define RED_OFF 155648
#define SMEMSZ  159744

__global__ __launch_bounds__(1024, 4) void fused_mhk(
    const float* __restrict__ x,
    const unsigned short* __restrict__ k_hi,
    const unsigned short* __restrict__ k_lo,
    const unsigned short* __restrict__ v_pk,
    float* __restrict__ out)
{
  extern __shared__ char smem[];
  const int tid  = threadIdx.x;
  const int wave = tid >> 6;
  const int lane = tid & 63;
  const int l31  = lane & 31;
  const int hi   = lane >> 5;

  const int bid = blockIdx.x;
  const int h   = bid & 7;        // head fixed per XCD slot
  const int g8  = bid >> 3;
  const int b   = g8 & 3;
  const int tt  = g8 >> 2;
  const int t0  = tt * 64;

  const unsigned short* kh2 = k_hi + (size_t)h * 131072;  // [s][n][16]
  const unsigned short* kl2 = k_lo + (size_t)h * 131072;
  float* red = (float*)(smem + RED_OFF);

  // ---- Phase 0: stage Q tile (hi bf16 + lo fp8) and async-stage K[0]
  {
    const float* xq = x + ((size_t)(b * 2048 + t0)) * 1024 + h * 128;
    const int r = tid >> 4, kc = tid & 15;
    const float* sp = xq + (size_t)r * 1024 + kc * 8;
    const float4 f0 = *(const float4*)sp;
    const float4 f1 = *(const float4*)(sp + 4);
    const float fv[8] = {f0.x, f0.y, f0.z, f0.w, f1.x, f1.y, f1.z, f1.w};
    bf16x8 hv; float lv[8];
#pragma unroll
    for (int e = 0; e < 8; ++e) {
      const __bf16 hb = (__bf16)fv[e];
      hv[e] = hb;
      lv[e] = (fv[e] - (float)hb) * 1024.0f;
    }
    const int g = kc * 64 + (r ^ ((kc >> 1) & 7));
    *(bf16x8*)(smem + QHI_OFF + g * 16) = hv;
    unsigned int w0 = pack_fp8_pair<false>(lv[0], lv[1], 0u);
    w0 = pack_fp8_pair<true>(lv[2], lv[3], w0);
    unsigned int w1 = pack_fp8_pair<false>(lv[4], lv[5], 0u);
    w1 = pack_fp8_pair<true>(lv[6], lv[7], w1);
    *(uint2*)(smem + QLO_OFF + g * 8) = make_uint2(w0, w1);
  }
  {
    const unsigned short* sh = kh2 + wave * 1024 + lane * 8;
    const unsigned short* sl = kl2 + wave * 1024 + lane * 8;
    gload_lds16(sh,       smem + wave * 2048);
    gload_lds16(sh + 512, smem + wave * 2048 + 1024);
    gload_lds16(sl,       smem + 32768 + wave * 2048);
    gload_lds16(sl + 512, smem + 32768 + wave * 2048 + 1024);
  }
  __syncthreads();   // Q visible to all; K[0] drained (full barrier)

  // ---- Phase 1: QK^T, BARRIER-FREE per-wave pipelined loop.
  //      Wave w reads only the K rows it staged (n in [w*64, w*64+64)).
  f32x16 acc[2][2];
#pragma unroll
  for (int t = 0; t < 2; ++t)
#pragma unroll
    for (int qt = 0; qt < 2; ++qt)
#pragma unroll
      for (int e = 0; e < 16; ++e) acc[t][qt][e] = 0.f;

#pragma unroll
  for (int s = 0; s < 8; ++s) {
    // stage K[s+1] into the other buffer (stays in flight across this step)
    if (s < 7) {
      char* nxt = smem + ((s + 1) & 1) * 65536;
      const unsigned short* sh = kh2 + (s + 1) * 16384 + wave * 1024 + lane * 8;
      const unsigned short* sl = kl2 + (s + 1) * 16384 + wave * 1024 + lane * 8;
      gload_lds16(sh,       nxt + wave * 2048);
      gload_lds16(sh + 512, nxt + wave * 2048 + 1024);
      gload_lds16(sl,       nxt + 32768 + wave * 2048);
      gload_lds16(sl + 512, nxt + 32768 + wave * 2048 + 1024);
      // wait: stage(s) landed (<=4 outstanding = stage(s+1) only)
      asm volatile("s_waitcnt vmcnt(4)" ::: "memory");
    } else {
      asm volatile("s_waitcnt vmcnt(0)" ::: "memory");
    }
    __builtin_amdgcn_sched_barrier(0);

    const char* cur = smem + (s & 1) * 65536;
    // Q fragments (shared, staged in phase 0)
    const int gx0 = (2 * s + hi) * 64 + (l31 ^ s);
    const int gx1 = (2 * s + hi) * 64 + ((32 + l31) ^ s);
    const bf16x8 bqh0 = *(const bf16x8*)(smem + QHI_OFF + gx0 * 16);
    const bf16x8 bqh1 = *(const bf16x8*)(smem + QHI_OFF + gx1 * 16);
    const bf16x8 bql0 = dec_qlo(*(const uint2*)(smem + QLO_OFF + gx0 * 8));
    const bf16x8 bql1 = dec_qlo(*(const uint2*)(smem + QLO_OFF + gx1 * 8));
    // K fragments from this wave's private region
    const int na = wave * 64 + l31;
    const bf16x8 ah0 = *(const bf16x8*)(cur + na * 32 + hi * 16);
    const bf16x8 ah1 = *(const bf16x8*)(cur + (na + 32) * 32 + hi * 16);
    const bf16x8 al0 = *(const bf16x8*)(cur + 32768 + na * 32 + hi * 16);
    const bf16x8 al1 = *(const bf16x8*)(cur + 32768 + (na + 32) * 32 + hi * 16);

    __builtin_amdgcn_s_setprio(1);
    acc[0][0] = __builtin_amdgcn_mfma_f32_32x32x16_bf16(ah0, bqh0, acc[0][0], 0, 0, 0);
    acc[0][1] = __builtin_amdgcn_mfma_f32_32x32x16_bf16(ah0, bqh1, acc[0][1], 0, 0, 0);
    acc[0][0] = __builtin_amdgcn_mfma_f32_32x32x16_bf16(ah0, bql0, acc[0][0], 0, 0, 0);
    acc[0][1] = __builtin_amdgcn_mfma_f32_32x32x16_bf16(ah0, bql1, acc[0][1], 0, 0, 0);
    acc[0][0] = __builtin_amdgcn_mfma_f32_32x32x16_bf16(al0, bqh0, acc[0][0], 0, 0, 0);
    acc[0][1] = __builtin_amdgcn_mfma_f32_32x32x16_bf16(al0, bqh1, acc[0][1], 0, 0, 0);
    acc[1][0] = __builtin_amdgcn_mfma_f32_32x32x16_bf16(ah1, bqh0, acc[1][0], 0, 0, 0);
    acc[1][1] = __builtin_amdgcn_mfma_f32_32x32x16_bf16(ah1, bqh1, acc[1][1], 0, 0, 0);
    acc[1][0] = __builtin_amdgcn_mfma_f32_32x32x16_bf16(ah1, bql0, acc[1][0], 0, 0, 0);
    acc[1][1] = __builtin_amdgcn_mfma_f32_32x32x16_bf16(ah1, bql1, acc[1][1], 0, 0, 0);
    acc[1][0] = __builtin_amdgcn_mfma_f32_32x32x16_bf16(al1, bqh0, acc[1][0], 0, 0, 0);
    acc[1][1] = __builtin_amdgcn_mfma_f32_32x32x16_bf16(al1, bqh1, acc[1][1], 0, 0, 0);
    __builtin_amdgcn_s_setprio(0);
  }

  // ---- Phase 2: l2-norm -> scale -> GELU -> mean (per q-row)
  float ss0 = 0.f, ss1 = 0.f;
#pragma unroll
  for (int t = 0; t < 2; ++t)
#pragma unroll
    for (int e = 0; e < 16; ++e) {
      ss0 += acc[t][0][e] * acc[t][0][e];
      ss1 += acc[t][1][e] * acc[t][1][e];
    }
  ss0 += __shfl_xor(ss0, 32);
  ss1 += __shfl_xor(ss1, 32);
  red[wave * 64 + lane] = hi ? ss1 : ss0;
  __syncthreads();
  float sum0 = 0.f, sum1 = 0.f;
#pragma unroll
  for (int w = 0; w < 16; ++w) {
    sum0 += red[w * 64 + l31];
    sum1 += red[w * 64 + 32 + l31];
  }
  const float scale0 = 32.0f / fmaxf(sqrtf(sum0), 1e-8f);
  const float scale1 = 32.0f / fmaxf(sqrtf(sum1), 1e-8f);
  const float c707_0 = scale0 * 0.70710678118654752f;
  const float c707_1 = scale1 * 0.70710678118654752f;
  const float chalf0 = scale0 * 0.5f;
  const float chalf1 = scale1 * 0.5f;

  float gs0 = 0.f, gs1 = 0.f;
#pragma unroll
  for (int t = 0; t < 2; ++t)
#pragma unroll
    for (int e = 0; e < 16; e += 2) {
      f32x2 in0; in0.x = acc[t][0][e]; in0.y = acc[t][0][e + 1];
      const f32x2 g0 = gelu2(in0, c707_0, chalf0);
      acc[t][0][e] = g0.x; acc[t][0][e + 1] = g0.y;
      gs0 += g0.x + g0.y;
      f32x2 in1; in1.x = acc[t][1][e]; in1.y = acc[t][1][e + 1];
      const f32x2 g1 = gelu2(in1, c707_1, chalf1);
      acc[t][1][e] = g1.x; acc[t][1][e + 1] = g1.y;
      gs1 += g1.x + g1.y;
    }
  gs0 += __shfl_xor(gs0, 32);
  gs1 += __shfl_xor(gs1, 32);
  __syncthreads();                    // all red reads done before rewrite
  red[wave * 64 + lane] = hi ? gs1 : gs0;
  __syncthreads();
  float mean0 = 0.f, mean1 = 0.f;
#pragma unroll
  for (int w = 0; w < 16; ++w) {
    mean0 += red[w * 64 + l31];
    mean1 += red[w * 64 + 32 + l31];
  }
  mean0 *= (1.0f / 1024.0f);
  mean1 *= (1.0f / 1024.0f);

  // ---- Phase 3: mask (strict >) + bf16 pack -> S granules (over dead K bufs)
#pragma unroll
  for (int t = 0; t < 2; ++t) {
#pragma unroll
    for (int qt = 0; qt < 2; ++qt) {
      const float mn = qt ? mean1 : mean0;
      const int q = qt * 32 + l31;
#pragma unroll
      for (int gi = 0; gi < 4; ++gi) {
        float g0 = acc[t][qt][4 * gi + 0]; g0 = (g0 > mn) ? g0 : 0.f;
        float g1 = acc[t][qt][4 * gi + 1]; g1 = (g1 > mn) ? g1 : 0.f;
        float g2 = acc[t][qt][4 * gi + 2]; g2 = (g2 > mn) ? g2 : 0.f;
        float g3 = acc[t][qt][4 * gi + 3]; g3 = (g3 > mn) ? g3 : 0.f;
        uint2 pk;
        pk.x = (unsigned)bfbits((__bf16)g0) | ((unsigned)bfbits((__bf16)g1) << 16);
        pk.y = (unsigned)bfbits((__bf16)g2) | ((unsigned)bfbits((__bf16)g3) << 16);
        const int ng = wave * 8 + t * 4 + gi;
        const int swz = (t * 4 + gi) & 7;               // = ng & 7
        *(uint2*)(smem + (ng * 64 + (q ^ swz)) * 16 + hi * 8) = pk;
      }
    }
  }
  __syncthreads();

  // ---- Phase 4: PV on 8 waves, 32x32 tiles, V prefetched 1 ahead
  if (wave >= 8) return;
  const int qt2 = wave >> 2;
  const int vt  = wave & 3;
  const int q   = qt2 * 32 + l31;

  f32x16 o;
#pragma unroll
  for (int e = 0; e < 16; ++e) o[e] = 0.f;

  const unsigned short* vb = v_pk + (size_t)h * 131072 + (size_t)hi * 1024 +
                             (size_t)(vt * 32 + l31) * 8;
  bf16x8 vcur = *(const bf16x8*)(vb);
#pragma unroll 8
  for (int ks = 0; ks < 64; ++ks) {
    const int ng = 2 * ks + hi;
    const bf16x8 aa = *(const bf16x8*)(smem + (ng * 64 + (q ^ (ng & 7))) * 16);
    bf16x8 vn;
    if (ks < 63) vn = *(const bf16x8*)(vb + (size_t)(ks + 1) * 2048);
    o = __builtin_amdgcn_mfma_f32_32x32x16_bf16(aa, vcur, o, 0, 0, 0);
    if (ks < 63) vcur = vn;
  }

  float* op = out + ((size_t)(b * 2048 + t0 + qt2 * 32)) * 1024 +
              h * 128 + vt * 32 + l31;
#pragma unroll
  for (int r = 0; r < 16; ++r) {
    const int qr = (r & 3) + 8 * (r >> 2) + 4 * hi;
    op[(size_t)qr * 1024] = o[r];
  }
}

// ---------------- launch ----------------

extern "C" void kernel_launch(void* const* d_in, const int* in_sizes, int n_in,
                              void* d_out, int out_size, void* d_ws, size_t ws_size,
                              hipStream_t stream) {
  const float* x   = (const float*)d_in[0];  // [4][2048][1024]
  const float* key = (const float*)d_in[1];  // [8][1024][128]
  const float* val = (const float*)d_in[2];  // [8][1024][128]
  float* out = (float*)d_out;                // [4][2048][1024]

  if (ws_size < (size_t)6 * 1024 * 1024) return;  // need 6 MB scratch

  unsigned short* k_hi = (unsigned short*)d_ws;   // 1M shorts (2 MB)
  unsigned short* k_lo = k_hi + 1048576;          // 1M shorts
  unsigned short* v_pk = k_lo + 1048576;          // 1M shorts (frag-packed V)

  prep_kv<<<dim3(768), dim3(256), 0, stream>>>(key, val, k_hi, k_lo, v_pk);
  fused_mhk<<<dim3(1024), dim3(1024), SMEMSZ, stream>>>(x, k_hi, k_lo, v_pk, out);
}